// Round 2
// baseline (500.689 us; speedup 1.0000x reference)
//
#include <hip/hip_runtime.h>
#include <cmath>

// ---- chunking: S=192 tokens/chunk, m0 sequences L={21824,5440,1344,320} ----
#define SCH 192
#define NCB 152      // chunks per batch: 114+29+7+2
#define NCHUNK 1216  // 8 batches
// smem word offsets, m0 chunk path (stride-17 padded rows)
#define SW_IN 0        // 32x8
#define SW_CONVW 256   // 16x4
#define SW_CONVB 320
#define SW_XPROJ 336   // 33x16
#define SW_DTW 864
#define SW_DTB 880
#define SW_A 896       // 16x16  (A = -exp(Alog))
#define SW_D 1152
#define SW_OUTW 1168   // 8x16
#define SW_NG 1296
#define SW_NB 1304
#define SW_PW 1312     // 8x8
#define SW_PB 1376
#define SW_SKIP 1384
#define O_XI 1385      // 195 rows x17 (xi; reused for Cm in pass3)
#define O_DLT 4700     // 192x17 (delta; reused for y in pass3)
#define O_BM 7964      // 192x17
#define O_XC 11228     // 192x17
#define SMEM_TOT 14492 // words = 57,968 B  (<64KB/block, 2 blocks/CU)
// c5 (m1) path offsets (fits inside same smem)
#define V_IN 0
#define V_CONVW 1024
#define V_CONVB 1152
#define V_XPROJ 1184
#define V_DTW 2240
#define V_DTB 2272
#define V_A 2304
#define V_D 2816
#define V_OUTW 2848
#define V_NG 3360
#define V_NB 3376
#define V_PW 3392
#define V_PB 3648
#define V_SKIP 3664
#define V_XI 3668      // 64x33
#define V_XC 5780      // 64x33
#define V_DL 7892      // 64x33 (delta; reused for y)
#define V_BM 10004     // 64x17
#define V_CM 11092     // 64x17

struct Params {
  const float *t0, *t1, *t2, *t3, *t4;
  const float *in_w0,*conv_w0,*conv_b0,*xproj0,*dtw0,*dtb0,*Alog0,*D0,*outw0;
  const float *in_w1,*conv_w1,*conv_b1,*xproj1,*dtw1,*dtb1,*Alog1,*D1,*outw1;
  const float *ng,*nb,*pw,*pb,*n1g,*n1b,*p1w,*p1b,*skip;
  float* out;
  float *hloc, *sumdelta, *hstart;
};

__device__ __forceinline__ float softplusf(float x) { return x > 20.f ? x : log1pf(__expf(x)); }
__device__ __forceinline__ float siluf(float x) { return x * (1.f / (1.f + __expf(-x))); }

struct Loc { int k, pos, ch, hw, C; };

__device__ __forceinline__ Loc locate(int seq, int l) {
  Loc r;
  if (seq == 0) { r.ch = 0;
    if (l < 16384)      { r.k=0; r.pos=l;        r.hw=16384; r.C=8;  }
    else if (l < 20480) { r.k=1; r.pos=l-16384;  r.hw=4096;  r.C=16; }
    else if (l < 21504) { r.k=2; r.pos=l-20480;  r.hw=1024;  r.C=24; }
    else if (l < 21760) { r.k=3; r.pos=l-21504;  r.hw=256;   r.C=32; }
    else                { r.k=4; r.pos=l-21760;  r.hw=64;    r.C=48; }
  } else if (seq == 1) { r.ch = 8;
    if (l < 4096)       { r.k=1; r.pos=l;        r.hw=4096;  r.C=16; }
    else if (l < 5120)  { r.k=2; r.pos=l-4096;   r.hw=1024;  r.C=24; }
    else if (l < 5376)  { r.k=3; r.pos=l-5120;   r.hw=256;   r.C=32; }
    else                { r.k=4; r.pos=l-5376;   r.hw=64;    r.C=48; }
  } else if (seq == 2) { r.ch = 16;
    if (l < 1024)       { r.k=2; r.pos=l;        r.hw=1024;  r.C=24; }
    else if (l < 1280)  { r.k=3; r.pos=l-1024;   r.hw=256;   r.C=32; }
    else                { r.k=4; r.pos=l-1280;   r.hw=64;    r.C=48; }
  } else { r.ch = 24;
    if (l < 256)        { r.k=3; r.pos=l;        r.hw=256;   r.C=32; }
    else                { r.k=4; r.pos=l-256;    r.hw=64;    r.C=48; }
  }
  return r;
}

__device__ __forceinline__ const float* tsel(const Params& p, int k) {
  switch (k) { case 0: return p.t0; case 1: return p.t1; case 2: return p.t2;
               case 3: return p.t3; default: return p.t4; }
}
// flat offsets of output tensors (include batch dim!): sizes are
// 8*8*16384, 8*16*4096, 8*24*1024, 8*32*256, 8*48*64 -> total 1859584
__device__ __forceinline__ int outbase(int k) {
  switch (k) { case 0: return 0; case 1: return 1048576; case 2: return 1572864;
               case 3: return 1769472; default: return 1835008; }
}

__device__ __forceinline__ void gather8(const Params& p, int b, int seq, int l, float* c) {
  Loc lc = locate(seq, l);
  const float* t = tsel(p, lc.k);
  int base = (b * lc.C + lc.ch) * lc.hw + lc.pos;
  #pragma unroll
  for (int j = 0; j < 8; ++j) c[j] = t[base + j * lc.hw];
}

__device__ __forceinline__ void decode_bid(int bid, int& b, int& seq, int& l0, int& Sa) {
  b = bid / NCB;
  int r = bid - b * NCB;
  int c, L;
  if (r < 114)      { seq = 0; c = r;       L = 21824; }
  else if (r < 143) { seq = 1; c = r - 114; L = 5440;  }
  else if (r < 150) { seq = 2; c = r - 143; L = 1344;  }
  else              { seq = 3; c = r - 150; L = 320;   }
  l0 = c * SCH;
  int rem = L - l0;
  Sa = rem < SCH ? rem : SCH;
}

__device__ void load_w0(const Params& p, float* s, int tid) {
  for (int i = tid; i < 256; i += 256) s[SW_IN + i] = p.in_w0[i];
  for (int i = tid; i < 64;  i += 256) s[SW_CONVW + i] = p.conv_w0[i];
  for (int i = tid; i < 16;  i += 256) s[SW_CONVB + i] = p.conv_b0[i];
  for (int i = tid; i < 528; i += 256) s[SW_XPROJ + i] = p.xproj0[i];
  for (int i = tid; i < 16;  i += 256) s[SW_DTW + i] = p.dtw0[i];
  for (int i = tid; i < 16;  i += 256) s[SW_DTB + i] = p.dtb0[i];
  for (int i = tid; i < 256; i += 256) s[SW_A + i] = -__expf(p.Alog0[i]);
  for (int i = tid; i < 16;  i += 256) s[SW_D + i] = p.D0[i];
  for (int i = tid; i < 128; i += 256) s[SW_OUTW + i] = p.outw0[i];
  for (int i = tid; i < 8;   i += 256) s[SW_NG + i] = p.ng[i];
  for (int i = tid; i < 8;   i += 256) s[SW_NB + i] = p.nb[i];
  for (int i = tid; i < 64;  i += 256) s[SW_PW + i] = p.pw[i];
  for (int i = tid; i < 8;   i += 256) s[SW_PB + i] = p.pb[i];
  if (tid == 0) s[SW_SKIP] = p.skip[0];
}

// token-parallel per-chunk front end: gather -> in-proj -> causal conv -> silu
// -> x-proj (dt, B, optionally C) -> softplus delta.  Results in LDS rows (stride 17).
template <bool WANT_CM>
__device__ void stage1(const Params& p, float* s, int b, int seq, int l0, int Sa, int tid) {
  if (tid < Sa + 3) {                 // rows r <-> token l0-3+r (conv halo)
    int l = l0 - 3 + tid;
    float x8[8];
    if (l >= 0) gather8(p, b, seq, l, x8);
    else {
      #pragma unroll
      for (int j = 0; j < 8; ++j) x8[j] = 0.f;
    }
    #pragma unroll
    for (int i = 0; i < 16; ++i) {
      float a = 0.f;
      #pragma unroll
      for (int j = 0; j < 8; ++j) a = fmaf(s[SW_IN + i * 8 + j], x8[j], a);
      s[O_XI + tid * 17 + i] = a;
    }
  }
  __syncthreads();
  float xc[16];
  bool act = tid < Sa;
  if (act) {
    #pragma unroll
    for (int i = 0; i < 16; ++i) {
      float a = s[SW_CONVB + i];
      #pragma unroll
      for (int kk = 0; kk < 4; ++kk)
        a = fmaf(s[SW_CONVW + i * 4 + kk], s[O_XI + (tid + kk) * 17 + i], a);
      xc[i] = siluf(a);
      s[O_XC + tid * 17 + i] = xc[i];
    }
  }
  __syncthreads();                    // xi reads done before Cm overwrites O_XI
  if (act) {
    float dt = 0.f;
    #pragma unroll
    for (int i = 0; i < 16; ++i) dt = fmaf(s[SW_XPROJ + i], xc[i], dt);
    #pragma unroll
    for (int n = 0; n < 16; ++n) {
      float a = 0.f;
      #pragma unroll
      for (int i = 0; i < 16; ++i) a = fmaf(s[SW_XPROJ + (1 + n) * 16 + i], xc[i], a);
      s[O_BM + tid * 17 + n] = a;
    }
    if (WANT_CM) {
      #pragma unroll
      for (int n = 0; n < 16; ++n) {
        float a = 0.f;
        #pragma unroll
        for (int i = 0; i < 16; ++i) a = fmaf(s[SW_XPROJ + (17 + n) * 16 + i], xc[i], a);
        s[O_XI + tid * 17 + n] = a;
      }
    }
    #pragma unroll
    for (int d = 0; d < 16; ++d)
      s[O_DLT + tid * 17 + d] = softplusf(fmaf(dt, s[SW_DTW + d], s[SW_DTB + d]));
  }
  __syncthreads();
}

// ---- c5 / m1 path: whole sequence (L=64, di=32) in one block ----
__device__ void load_w1(const Params& p, float* s, int tid) {
  for (int i = tid; i < 1024; i += 256) s[V_IN + i] = p.in_w1[i];
  for (int i = tid; i < 128;  i += 256) s[V_CONVW + i] = p.conv_w1[i];
  for (int i = tid; i < 32;   i += 256) s[V_CONVB + i] = p.conv_b1[i];
  for (int i = tid; i < 1056; i += 256) s[V_XPROJ + i] = p.xproj1[i];
  for (int i = tid; i < 32;   i += 256) s[V_DTW + i] = p.dtw1[i];
  for (int i = tid; i < 32;   i += 256) s[V_DTB + i] = p.dtb1[i];
  for (int i = tid; i < 512;  i += 256) s[V_A + i] = -__expf(p.Alog1[i]);
  for (int i = tid; i < 32;   i += 256) s[V_D + i] = p.D1[i];
  for (int i = tid; i < 512;  i += 256) s[V_OUTW + i] = p.outw1[i];
  for (int i = tid; i < 16;   i += 256) s[V_NG + i] = p.n1g[i];
  for (int i = tid; i < 16;   i += 256) s[V_NB + i] = p.n1b[i];
  for (int i = tid; i < 256;  i += 256) s[V_PW + i] = p.p1w[i];
  for (int i = tid; i < 16;   i += 256) s[V_PB + i] = p.p1b[i];
  if (tid == 0) s[V_SKIP] = p.skip[0];
}

__device__ void c5_path(const Params& p, float* s, int b, int tid) {
  load_w1(p, s, tid);
  __syncthreads();
  float x16[16];
  bool act = tid < 64;
  if (act) {
    #pragma unroll
    for (int j = 0; j < 16; ++j) x16[j] = p.t4[(b * 48 + 32 + j) * 64 + tid];
    #pragma unroll
    for (int i = 0; i < 32; ++i) {
      float a = 0.f;
      #pragma unroll
      for (int j = 0; j < 16; ++j) a = fmaf(s[V_IN + i * 16 + j], x16[j], a);
      s[V_XI + tid * 33 + i] = a;
    }
  }
  __syncthreads();
  if (act) {
    float xc[32];
    #pragma unroll
    for (int i = 0; i < 32; ++i) {
      float a = s[V_CONVB + i];
      #pragma unroll
      for (int kk = 0; kk < 4; ++kk) {
        int r = tid + kk - 3;
        if (r >= 0) a = fmaf(s[V_CONVW + i * 4 + kk], s[V_XI + r * 33 + i], a);
      }
      xc[i] = siluf(a);
      s[V_XC + tid * 33 + i] = xc[i];
    }
    float dt = 0.f;
    #pragma unroll
    for (int i = 0; i < 32; ++i) dt = fmaf(s[V_XPROJ + i], xc[i], dt);
    #pragma unroll
    for (int n = 0; n < 16; ++n) {
      float a = 0.f, c = 0.f;
      #pragma unroll
      for (int i = 0; i < 32; ++i) {
        a = fmaf(s[V_XPROJ + (1 + n) * 32 + i], xc[i], a);
        c = fmaf(s[V_XPROJ + (17 + n) * 32 + i], xc[i], c);
      }
      s[V_BM + tid * 17 + n] = a;
      s[V_CM + tid * 17 + n] = c;
    }
    #pragma unroll
    for (int d = 0; d < 32; ++d)
      s[V_DL + tid * 33 + d] = softplusf(fmaf(dt, s[V_DTW + d], s[V_DTB + d]));
  }
  __syncthreads();
  // scan: thread handles states (d0,n) and (d0+16,n); the 16 threads of a
  // d0-column sit in one wave => in-order LDS reuse of V_DL column as y.
  int d0 = tid >> 4, n = tid & 15;
  float a0 = s[V_A + d0 * 16 + n], a1 = s[V_A + (d0 + 16) * 16 + n];
  float h0 = 0.f, h1 = 0.f;
  for (int l = 0; l < 64; ++l) {
    float dl0 = s[V_DL + l * 33 + d0];
    float dl1 = s[V_DL + l * 33 + d0 + 16];
    float bm  = s[V_BM + l * 17 + n];
    float cm  = s[V_CM + l * 17 + n];
    float xv0 = s[V_XC + l * 33 + d0];
    float xv1 = s[V_XC + l * 33 + d0 + 16];
    h0 = fmaf(__expf(a0 * dl0), h0, dl0 * bm * xv0);
    h1 = fmaf(__expf(a1 * dl1), h1, dl1 * bm * xv1);
    float y0 = h0 * cm, y1 = h1 * cm;
    #pragma unroll
    for (int m = 1; m < 16; m <<= 1) { y0 += __shfl_xor(y0, m); y1 += __shfl_xor(y1, m); }
    if (n == 0) { s[V_DL + l * 33 + d0] = y0; s[V_DL + l * 33 + d0 + 16] = y1; }
  }
  __syncthreads();
  if (act) {
    float y[32];
    #pragma unroll
    for (int d = 0; d < 32; ++d) {
      float z = 0.f;
      #pragma unroll
      for (int j = 0; j < 16; ++j) z = fmaf(s[V_IN + (32 + d) * 16 + j], x16[j], z);
      y[d] = (s[V_DL + tid * 33 + d] + s[V_XC + tid * 33 + d] * s[V_D + d]) * siluf(z);
    }
    float o[16];
    float sk = s[V_SKIP];
    #pragma unroll
    for (int m = 0; m < 16; ++m) {
      float a = 0.f;
      #pragma unroll
      for (int d = 0; d < 32; ++d) a = fmaf(s[V_OUTW + m * 32 + d], y[d], a);
      o[m] = a + sk * x16[m];
    }
    float mu = 0.f;
    #pragma unroll
    for (int m = 0; m < 16; ++m) mu += o[m];
    mu *= (1.f / 16.f);
    float var = 0.f;
    #pragma unroll
    for (int m = 0; m < 16; ++m) { float t = o[m] - mu; var += t * t; }
    var *= (1.f / 16.f);
    float inv = rsqrtf(var + 1e-5f);
    float ln[16];
    #pragma unroll
    for (int m = 0; m < 16; ++m) ln[m] = (o[m] - mu) * inv * s[V_NG + m] + s[V_NB + m];
    #pragma unroll
    for (int m = 0; m < 16; ++m) {
      float a = s[V_PB + m];
      #pragma unroll
      for (int j = 0; j < 16; ++j) a = fmaf(s[V_PW + m * 16 + j], ln[j], a);
      p.out[1835008 + (b * 48 + 32 + m) * 64 + tid] = a;
    }
  }
}

// pass 1: per-chunk local scan (h from 0) -> h_local_end + per-d delta sums
__global__ __launch_bounds__(256) void k_pass1(Params p) {
  __shared__ float s[SMEM_TOT];
  int bid = blockIdx.x, tid = threadIdx.x;
  if (bid >= NCHUNK) { c5_path(p, s, bid - NCHUNK, tid); return; }
  int b, seq, l0, Sa;
  decode_bid(bid, b, seq, l0, Sa);
  load_w0(p, s, tid);
  __syncthreads();
  stage1<false>(p, s, b, seq, l0, Sa, tid);
  int d = tid >> 4, n = tid & 15;
  float A_dn = s[SW_A + d * 16 + n];
  float h = 0.f, sd = 0.f;
  float dl = s[O_DLT + d], bm = s[O_BM + n], xv = s[O_XC + d];
  for (int l = 0; l < Sa; ++l) {
    int lp = (l + 1 < Sa) ? (l + 1) : (Sa - 1);
    float dl2 = s[O_DLT + lp * 17 + d];
    float bm2 = s[O_BM + lp * 17 + n];
    float xv2 = s[O_XC + lp * 17 + d];
    h = fmaf(__expf(A_dn * dl), h, dl * bm * xv);
    sd += dl;
    dl = dl2; bm = bm2; xv = xv2;
  }
  p.hloc[(size_t)bid * 256 + tid] = h;
  if (n == 0) p.sumdelta[(size_t)bid * 16 + d] = sd;
}

// pass 2: sequential cross-chunk combine per (batch, seq): h' = exp(A*sumd)*h + hloc
__global__ __launch_bounds__(256) void k_pass2(Params p) {
  int bid = blockIdx.x, tid = threadIdx.x;
  int b = bid >> 2, seq = bid & 3;
  const int nch[4] = {114, 29, 7, 2};
  const int chf[4] = {0, 114, 143, 150};
  int nc = nch[seq];
  int g0 = b * NCB + chf[seq];
  int d = tid >> 4, n = tid & 15;
  float A_dn = -__expf(p.Alog0[d * 16 + n]);
  float h = 0.f;
  for (int c = 0; c < nc; ++c) {
    int g = g0 + c;
    p.hstart[(size_t)g * 256 + tid] = h;
    float sd = p.sumdelta[(size_t)g * 16 + d];
    float hl = p.hloc[(size_t)g * 256 + tid];
    h = fmaf(__expf(A_dn * sd), h, hl);
  }
}

// pass 3: rerun scan from h_start, produce y, fuse gate+out-proj+skip+LN+proj, scatter
__global__ __launch_bounds__(256) void k_pass3(Params p) {
  __shared__ float s[SMEM_TOT];
  int bid = blockIdx.x, tid = threadIdx.x;
  int b, seq, l0, Sa;
  decode_bid(bid, b, seq, l0, Sa);
  load_w0(p, s, tid);
  __syncthreads();
  stage1<true>(p, s, b, seq, l0, Sa, tid);
  int d = tid >> 4, n = tid & 15;
  float A_dn = s[SW_A + d * 16 + n];
  float h = p.hstart[(size_t)bid * 256 + tid];
  float dl = s[O_DLT + d], bm = s[O_BM + n], xv = s[O_XC + d], cm = s[O_XI + n];
  for (int l = 0; l < Sa; ++l) {
    int lp = (l + 1 < Sa) ? (l + 1) : (Sa - 1);
    float dl2 = s[O_DLT + lp * 17 + d];
    float bm2 = s[O_BM + lp * 17 + n];
    float xv2 = s[O_XC + lp * 17 + d];
    float cm2 = s[O_XI + lp * 17 + n];
    h = fmaf(__expf(A_dn * dl), h, dl * bm * xv);
    float yp = h * cm;
    yp += __shfl_xor(yp, 1);
    yp += __shfl_xor(yp, 2);
    yp += __shfl_xor(yp, 4);
    yp += __shfl_xor(yp, 8);
    if (n == 0) s[O_DLT + l * 17 + d] = yp;   // reuse delta row l as y (in-order per wave)
    dl = dl2; bm = bm2; xv = xv2; cm = cm2;
  }
  __syncthreads();
  if (tid < Sa) {
    int l = l0 + tid;
    float c8[8];
    gather8(p, b, seq, l, c8);
    float y[16];
    #pragma unroll
    for (int i = 0; i < 16; ++i) {
      float z = 0.f;
      #pragma unroll
      for (int j = 0; j < 8; ++j) z = fmaf(s[SW_IN + (16 + i) * 8 + j], c8[j], z);
      y[i] = (s[O_DLT + tid * 17 + i] + s[O_XC + tid * 17 + i] * s[SW_D + i]) * siluf(z);
    }
    float o[8];
    float sk = s[SW_SKIP];
    #pragma unroll
    for (int m = 0; m < 8; ++m) {
      float a = 0.f;
      #pragma unroll
      for (int dd = 0; dd < 16; ++dd) a = fmaf(s[SW_OUTW + m * 16 + dd], y[dd], a);
      o[m] = a + sk * c8[m];
    }
    float mu = 0.f;
    #pragma unroll
    for (int m = 0; m < 8; ++m) mu += o[m];
    mu *= 0.125f;
    float var = 0.f;
    #pragma unroll
    for (int m = 0; m < 8; ++m) { float t = o[m] - mu; var += t * t; }
    var *= 0.125f;
    float inv = rsqrtf(var + 1e-5f);
    float ln[8];
    #pragma unroll
    for (int m = 0; m < 8; ++m) ln[m] = (o[m] - mu) * inv * s[SW_NG + m] + s[SW_NB + m];
    Loc lc = locate(seq, l);
    int obase = outbase(lc.k) + (b * lc.C + lc.ch) * lc.hw + lc.pos;
    #pragma unroll
    for (int m = 0; m < 8; ++m) {
      float a = s[SW_PB + m];
      #pragma unroll
      for (int j = 0; j < 8; ++j) a = fmaf(s[SW_PW + m * 8 + j], ln[j], a);
      p.out[obase + m * lc.hw] = a;
    }
  }
}

extern "C" void kernel_launch(void* const* d_in, const int* in_sizes, int n_in,
                              void* d_out, int out_size, void* d_ws, size_t ws_size,
                              hipStream_t stream) {
  (void)in_sizes; (void)n_in; (void)out_size; (void)ws_size;
  Params p;
  p.t0 = (const float*)d_in[0];  p.t1 = (const float*)d_in[1];
  p.t2 = (const float*)d_in[2];  p.t3 = (const float*)d_in[3];
  p.t4 = (const float*)d_in[4];
  p.in_w0   = (const float*)d_in[5];
  p.conv_w0 = (const float*)d_in[6];
  p.conv_b0 = (const float*)d_in[7];
  p.xproj0  = (const float*)d_in[8];
  p.dtw0    = (const float*)d_in[9];
  p.dtb0    = (const float*)d_in[10];
  p.Alog0   = (const float*)d_in[11];
  p.D0      = (const float*)d_in[12];
  p.outw0   = (const float*)d_in[13];
  p.in_w1   = (const float*)d_in[14];
  p.conv_w1 = (const float*)d_in[15];
  p.conv_b1 = (const float*)d_in[16];
  p.xproj1  = (const float*)d_in[17];
  p.dtw1    = (const float*)d_in[18];
  p.dtb1    = (const float*)d_in[19];
  p.Alog1   = (const float*)d_in[20];
  p.D1      = (const float*)d_in[21];
  p.outw1   = (const float*)d_in[22];
  p.ng  = (const float*)d_in[23];
  p.nb  = (const float*)d_in[24];
  p.pw  = (const float*)d_in[25];
  p.pb  = (const float*)d_in[26];
  p.n1g = (const float*)d_in[27];
  p.n1b = (const float*)d_in[28];
  p.p1w = (const float*)d_in[29];
  p.p1b = (const float*)d_in[30];
  p.skip = (const float*)d_in[31];
  p.out = (float*)d_out;
  float* ws = (float*)d_ws;
  p.hloc     = ws;
  p.sumdelta = ws + (size_t)NCHUNK * 256;
  p.hstart   = ws + (size_t)NCHUNK * 256 + (size_t)NCHUNK * 16;
  k_pass1<<<dim3(NCHUNK + 8), dim3(256), 0, stream>>>(p);
  k_pass2<<<dim3(32), dim3(256), 0, stream>>>(p);
  k_pass3<<<dim3(NCHUNK), dim3(256), 0, stream>>>(p);
}

// Round 3
// 452.418 us; speedup vs baseline: 1.1067x; 1.1067x over previous
//
#include <hip/hip_runtime.h>
#include <cmath>

// ---- chunking: SCH=168 tokens/chunk, 4 sub-chunks of 42 (one per wave) ----
// m0 sequences L={21824,5440,1344,320} -> chunks {130,33,8,2} per batch
#define SCH 168
#define SUB 42
#define NCB 173      // chunks per batch: 130+33+8+2
#define NCHUNK 1384  // 8 batches
#define NSUB 5536    // 4*NCHUNK
// smem word offsets, m0 chunk path (stride-17 padded rows)
#define SW_IN 0        // 32x8
#define SW_CONVW 256   // 16x4
#define SW_CONVB 320
#define SW_XPROJ 336   // 33x16
#define SW_DTW 864
#define SW_DTB 880
#define SW_A 896       // 16x16  (A = -exp(Alog))
#define SW_D 1152
#define SW_OUTW 1168   // 8x16
#define SW_NG 1296
#define SW_NB 1304
#define SW_PW 1312     // 8x8
#define SW_PB 1376
#define SW_SKIP 1384
#define O_XI 1385      // 171 rows x17 (xi; reused for Cm in pass3)
#define O_DLT 4292     // 168x17 (delta; reused for y in pass3)
#define O_BM 7148      // 168x17
#define O_XC 10004     // 168x17
#define SMEM_TOT 12860 // words = 51,440 B  -> 3 blocks/CU
// c5 (m1) path offsets (fits inside same smem)
#define V_IN 0
#define V_CONVW 1024
#define V_CONVB 1152
#define V_XPROJ 1184
#define V_DTW 2240
#define V_DTB 2272
#define V_A 2304
#define V_D 2816
#define V_OUTW 2848
#define V_NG 3360
#define V_NB 3376
#define V_PW 3392
#define V_PB 3648
#define V_SKIP 3664
#define V_XI 3668      // 64x33
#define V_XC 5780      // 64x33
#define V_DL 7892      // 64x33 (delta; reused for y)
#define V_BM 10004     // 64x17
#define V_CM 11092     // 64x17

struct Params {
  const float *t0, *t1, *t2, *t3, *t4;
  const float *in_w0,*conv_w0,*conv_b0,*xproj0,*dtw0,*dtb0,*Alog0,*D0,*outw0;
  const float *in_w1,*conv_w1,*conv_b1,*xproj1,*dtw1,*dtb1,*Alog1,*D1,*outw1;
  const float *ng,*nb,*pw,*pb,*n1g,*n1b,*p1w,*p1b,*skip;
  float* out;
  float *hloc, *sumdelta;   // hloc reused as hstart (pass2 writes in place)
};

__device__ __forceinline__ float softplusf(float x) { return x > 20.f ? x : log1pf(__expf(x)); }
__device__ __forceinline__ float siluf(float x) { return x * (1.f / (1.f + __expf(-x))); }

struct Loc { int k, pos, ch, hw, C; };

__device__ __forceinline__ Loc locate(int seq, int l) {
  Loc r;
  if (seq == 0) { r.ch = 0;
    if (l < 16384)      { r.k=0; r.pos=l;        r.hw=16384; r.C=8;  }
    else if (l < 20480) { r.k=1; r.pos=l-16384;  r.hw=4096;  r.C=16; }
    else if (l < 21504) { r.k=2; r.pos=l-20480;  r.hw=1024;  r.C=24; }
    else if (l < 21760) { r.k=3; r.pos=l-21504;  r.hw=256;   r.C=32; }
    else                { r.k=4; r.pos=l-21760;  r.hw=64;    r.C=48; }
  } else if (seq == 1) { r.ch = 8;
    if (l < 4096)       { r.k=1; r.pos=l;        r.hw=4096;  r.C=16; }
    else if (l < 5120)  { r.k=2; r.pos=l-4096;   r.hw=1024;  r.C=24; }
    else if (l < 5376)  { r.k=3; r.pos=l-5120;   r.hw=256;   r.C=32; }
    else                { r.k=4; r.pos=l-5376;   r.hw=64;    r.C=48; }
  } else if (seq == 2) { r.ch = 16;
    if (l < 1024)       { r.k=2; r.pos=l;        r.hw=1024;  r.C=24; }
    else if (l < 1280)  { r.k=3; r.pos=l-1024;   r.hw=256;   r.C=32; }
    else                { r.k=4; r.pos=l-1280;   r.hw=64;    r.C=48; }
  } else { r.ch = 24;
    if (l < 256)        { r.k=3; r.pos=l;        r.hw=256;   r.C=32; }
    else                { r.k=4; r.pos=l-256;    r.hw=64;    r.C=48; }
  }
  return r;
}

__device__ __forceinline__ const float* tsel(const Params& p, int k) {
  switch (k) { case 0: return p.t0; case 1: return p.t1; case 2: return p.t2;
               case 3: return p.t3; default: return p.t4; }
}
// flat offsets of output tensors (with batch dim): total 1859584
__device__ __forceinline__ int outbase(int k) {
  switch (k) { case 0: return 0; case 1: return 1048576; case 2: return 1572864;
               case 3: return 1769472; default: return 1835008; }
}

__device__ __forceinline__ void gather8(const Params& p, int b, int seq, int l, float* c) {
  Loc lc = locate(seq, l);
  const float* t = tsel(p, lc.k);
  int base = (b * lc.C + lc.ch) * lc.hw + lc.pos;
  #pragma unroll
  for (int j = 0; j < 8; ++j) c[j] = t[base + j * lc.hw];
}

__device__ __forceinline__ void decode_bid(int bid, int& b, int& seq, int& l0, int& Sa) {
  b = bid / NCB;
  int r = bid - b * NCB;
  int c, L;
  if (r < 130)      { seq = 0; c = r;       L = 21824; }
  else if (r < 163) { seq = 1; c = r - 130; L = 5440;  }
  else if (r < 171) { seq = 2; c = r - 163; L = 1344;  }
  else              { seq = 3; c = r - 171; L = 320;   }
  l0 = c * SCH;
  int rem = L - l0;
  Sa = rem < SCH ? rem : SCH;
}

__device__ void load_w0(const Params& p, float* s, int tid) {
  for (int i = tid; i < 256; i += 256) s[SW_IN + i] = p.in_w0[i];
  for (int i = tid; i < 64;  i += 256) s[SW_CONVW + i] = p.conv_w0[i];
  for (int i = tid; i < 16;  i += 256) s[SW_CONVB + i] = p.conv_b0[i];
  for (int i = tid; i < 528; i += 256) s[SW_XPROJ + i] = p.xproj0[i];
  for (int i = tid; i < 16;  i += 256) s[SW_DTW + i] = p.dtw0[i];
  for (int i = tid; i < 16;  i += 256) s[SW_DTB + i] = p.dtb0[i];
  for (int i = tid; i < 256; i += 256) s[SW_A + i] = -__expf(p.Alog0[i]);
  for (int i = tid; i < 16;  i += 256) s[SW_D + i] = p.D0[i];
  for (int i = tid; i < 128; i += 256) s[SW_OUTW + i] = p.outw0[i];
  for (int i = tid; i < 8;   i += 256) s[SW_NG + i] = p.ng[i];
  for (int i = tid; i < 8;   i += 256) s[SW_NB + i] = p.nb[i];
  for (int i = tid; i < 64;  i += 256) s[SW_PW + i] = p.pw[i];
  for (int i = tid; i < 8;   i += 256) s[SW_PB + i] = p.pb[i];
  if (tid == 0) s[SW_SKIP] = p.skip[0];
}

// token-parallel per-chunk front end: gather -> in-proj -> causal conv -> silu
// -> x-proj (dt, B, optionally C) -> softplus delta.  Results in LDS rows (stride 17).
template <bool WANT_CM>
__device__ void stage1(const Params& p, float* s, int b, int seq, int l0, int Sa, int tid) {
  if (tid < Sa + 3) {                 // rows r <-> token l0-3+r (conv halo)
    int l = l0 - 3 + tid;
    float x8[8];
    if (l >= 0) gather8(p, b, seq, l, x8);
    else {
      #pragma unroll
      for (int j = 0; j < 8; ++j) x8[j] = 0.f;
    }
    #pragma unroll
    for (int i = 0; i < 16; ++i) {
      float a = 0.f;
      #pragma unroll
      for (int j = 0; j < 8; ++j) a = fmaf(s[SW_IN + i * 8 + j], x8[j], a);
      s[O_XI + tid * 17 + i] = a;
    }
  }
  __syncthreads();
  float xc[16];
  bool act = tid < Sa;
  if (act) {
    #pragma unroll
    for (int i = 0; i < 16; ++i) {
      float a = s[SW_CONVB + i];
      #pragma unroll
      for (int kk = 0; kk < 4; ++kk)
        a = fmaf(s[SW_CONVW + i * 4 + kk], s[O_XI + (tid + kk) * 17 + i], a);
      xc[i] = siluf(a);
      s[O_XC + tid * 17 + i] = xc[i];
    }
  }
  __syncthreads();                    // xi reads done before Cm overwrites O_XI
  if (act) {
    float dt = 0.f;
    #pragma unroll
    for (int i = 0; i < 16; ++i) dt = fmaf(s[SW_XPROJ + i], xc[i], dt);
    #pragma unroll
    for (int n = 0; n < 16; ++n) {
      float a = 0.f;
      #pragma unroll
      for (int i = 0; i < 16; ++i) a = fmaf(s[SW_XPROJ + (1 + n) * 16 + i], xc[i], a);
      s[O_BM + tid * 17 + n] = a;
    }
    if (WANT_CM) {
      #pragma unroll
      for (int n = 0; n < 16; ++n) {
        float a = 0.f;
        #pragma unroll
        for (int i = 0; i < 16; ++i) a = fmaf(s[SW_XPROJ + (17 + n) * 16 + i], xc[i], a);
        s[O_XI + tid * 17 + n] = a;
      }
    }
    #pragma unroll
    for (int d = 0; d < 16; ++d)
      s[O_DLT + tid * 17 + d] = softplusf(fmaf(dt, s[SW_DTW + d], s[SW_DTB + d]));
  }
  __syncthreads();
}

// ---- c5 / m1 path: whole sequence (L=64, di=32) in one block ----
__device__ void load_w1(const Params& p, float* s, int tid) {
  for (int i = tid; i < 1024; i += 256) s[V_IN + i] = p.in_w1[i];
  for (int i = tid; i < 128;  i += 256) s[V_CONVW + i] = p.conv_w1[i];
  for (int i = tid; i < 32;   i += 256) s[V_CONVB + i] = p.conv_b1[i];
  for (int i = tid; i < 1056; i += 256) s[V_XPROJ + i] = p.xproj1[i];
  for (int i = tid; i < 32;   i += 256) s[V_DTW + i] = p.dtw1[i];
  for (int i = tid; i < 32;   i += 256) s[V_DTB + i] = p.dtb1[i];
  for (int i = tid; i < 512;  i += 256) s[V_A + i] = -__expf(p.Alog1[i]);
  for (int i = tid; i < 32;   i += 256) s[V_D + i] = p.D1[i];
  for (int i = tid; i < 512;  i += 256) s[V_OUTW + i] = p.outw1[i];
  for (int i = tid; i < 16;   i += 256) s[V_NG + i] = p.n1g[i];
  for (int i = tid; i < 16;   i += 256) s[V_NB + i] = p.n1b[i];
  for (int i = tid; i < 256;  i += 256) s[V_PW + i] = p.p1w[i];
  for (int i = tid; i < 16;   i += 256) s[V_PB + i] = p.p1b[i];
  if (tid == 0) s[V_SKIP] = p.skip[0];
}

__device__ void c5_path(const Params& p, float* s, int b, int tid) {
  load_w1(p, s, tid);
  __syncthreads();
  float x16[16];
  bool act = tid < 64;
  if (act) {
    #pragma unroll
    for (int j = 0; j < 16; ++j) x16[j] = p.t4[(b * 48 + 32 + j) * 64 + tid];
    #pragma unroll
    for (int i = 0; i < 32; ++i) {
      float a = 0.f;
      #pragma unroll
      for (int j = 0; j < 16; ++j) a = fmaf(s[V_IN + i * 16 + j], x16[j], a);
      s[V_XI + tid * 33 + i] = a;
    }
  }
  __syncthreads();
  if (act) {
    float xc[32];
    #pragma unroll
    for (int i = 0; i < 32; ++i) {
      float a = s[V_CONVB + i];
      #pragma unroll
      for (int kk = 0; kk < 4; ++kk) {
        int r = tid + kk - 3;
        if (r >= 0) a = fmaf(s[V_CONVW + i * 4 + kk], s[V_XI + r * 33 + i], a);
      }
      xc[i] = siluf(a);
      s[V_XC + tid * 33 + i] = xc[i];
    }
    float dt = 0.f;
    #pragma unroll
    for (int i = 0; i < 32; ++i) dt = fmaf(s[V_XPROJ + i], xc[i], dt);
    #pragma unroll
    for (int n = 0; n < 16; ++n) {
      float a = 0.f, c = 0.f;
      #pragma unroll
      for (int i = 0; i < 32; ++i) {
        a = fmaf(s[V_XPROJ + (1 + n) * 32 + i], xc[i], a);
        c = fmaf(s[V_XPROJ + (17 + n) * 32 + i], xc[i], c);
      }
      s[V_BM + tid * 17 + n] = a;
      s[V_CM + tid * 17 + n] = c;
    }
    #pragma unroll
    for (int d = 0; d < 32; ++d)
      s[V_DL + tid * 33 + d] = softplusf(fmaf(dt, s[V_DTW + d], s[V_DTB + d]));
  }
  __syncthreads();
  // scan: 128 threads, thread owns (d, 4 n-states) in registers; reduction
  // over n = 3 in-register fmas + 2 quad shuffles. d 0..15 wave0, 16..31 wave1
  // -> each wave reads/writes a disjoint V_DL column range (in-order safe).
  if (tid < 128) {
    int d = tid >> 2, ng = tid & 3;
    float A_[4], h_[4];
    #pragma unroll
    for (int j = 0; j < 4; ++j) { A_[j] = s[V_A + d * 16 + ng * 4 + j]; h_[j] = 0.f; }
    for (int l = 0; l < 64; ++l) {
      float dl = s[V_DL + l * 33 + d];
      float xv = s[V_XC + l * 33 + d];
      float u = dl * xv;
      float y = 0.f;
      #pragma unroll
      for (int j = 0; j < 4; ++j) {
        float bm = s[V_BM + l * 17 + ng * 4 + j];
        float cm = s[V_CM + l * 17 + ng * 4 + j];
        h_[j] = fmaf(__expf(A_[j] * dl), h_[j], u * bm);
        y = fmaf(h_[j], cm, y);
      }
      y += __shfl_xor(y, 1);
      y += __shfl_xor(y, 2);
      if (ng == 0) s[V_DL + l * 33 + d] = y;
    }
  }
  __syncthreads();
  if (act) {
    float y[32];
    #pragma unroll
    for (int d = 0; d < 32; ++d) {
      float z = 0.f;
      #pragma unroll
      for (int j = 0; j < 16; ++j) z = fmaf(s[V_IN + (32 + d) * 16 + j], x16[j], z);
      y[d] = (s[V_DL + tid * 33 + d] + s[V_XC + tid * 33 + d] * s[V_D + d]) * siluf(z);
    }
    float o[16];
    float sk = s[V_SKIP];
    #pragma unroll
    for (int m = 0; m < 16; ++m) {
      float a = 0.f;
      #pragma unroll
      for (int d = 0; d < 32; ++d) a = fmaf(s[V_OUTW + m * 32 + d], y[d], a);
      o[m] = a + sk * x16[m];
    }
    float mu = 0.f;
    #pragma unroll
    for (int m = 0; m < 16; ++m) mu += o[m];
    mu *= (1.f / 16.f);
    float var = 0.f;
    #pragma unroll
    for (int m = 0; m < 16; ++m) { float t = o[m] - mu; var += t * t; }
    var *= (1.f / 16.f);
    float inv = rsqrtf(var + 1e-5f);
    float ln[16];
    #pragma unroll
    for (int m = 0; m < 16; ++m) ln[m] = (o[m] - mu) * inv * s[V_NG + m] + s[V_NB + m];
    #pragma unroll
    for (int m = 0; m < 16; ++m) {
      float a = s[V_PB + m];
      #pragma unroll
      for (int j = 0; j < 16; ++j) a = fmaf(s[V_PW + m * 16 + j], ln[j], a);
      p.out[1835008 + (b * 48 + 32 + m) * 64 + tid] = a;
    }
  }
}

// pass 1: per-sub-chunk local scan (h from 0) -> h_local_end + per-d delta sums
// block = chunk of 168 tokens; 4 waves = 4 sub-chunks of 42.
__global__ __launch_bounds__(256) void k_pass1(Params p) {
  __shared__ float s[SMEM_TOT];
  int bid = blockIdx.x, tid = threadIdx.x;
  if (bid < 8) { c5_path(p, s, bid, tid); return; }   // c5 first: no straggler tail
  int cid = bid - 8;
  int b, seq, l0, Sa;
  decode_bid(cid, b, seq, l0, Sa);
  load_w0(p, s, tid);
  __syncthreads();
  stage1<false>(p, s, b, seq, l0, Sa, tid);
  int w = tid >> 6, lane = tid & 63;
  int d = lane >> 2, ng = lane & 3;
  int t0 = w * SUB;
  int len = Sa - t0; len = len < 0 ? 0 : (len > SUB ? SUB : len);
  float A_[4], h_[4];
  #pragma unroll
  for (int j = 0; j < 4; ++j) { A_[j] = s[SW_A + d * 16 + ng * 4 + j]; h_[j] = 0.f; }
  float sd = 0.f;
  for (int i = 0; i < len; ++i) {
    int t = t0 + i;
    float dl = s[O_DLT + t * 17 + d];
    float xv = s[O_XC + t * 17 + d];
    float u = dl * xv;
    #pragma unroll
    for (int j = 0; j < 4; ++j) {
      float bm = s[O_BM + t * 17 + ng * 4 + j];
      h_[j] = fmaf(__expf(A_[j] * dl), h_[j], u * bm);
    }
    sd += dl;
  }
  int gs = cid * 4 + w;
  #pragma unroll
  for (int j = 0; j < 4; ++j)
    p.hloc[(size_t)gs * 256 + d * 16 + ng * 4 + j] = h_[j];
  if (ng == 0) p.sumdelta[(size_t)gs * 16 + d] = sd;
}

// pass 2: sequential cross-sub-chunk combine per (batch, seq):
// h' = exp(A*sumd)*h + hloc; writes h_start IN PLACE over hloc.
__global__ __launch_bounds__(256) void k_pass2(Params p) {
  int bid = blockIdx.x, tid = threadIdx.x;
  int b = bid >> 2, seq = bid & 3;
  const int nch[4] = {130, 33, 8, 2};
  const int chf[4] = {0, 130, 163, 171};
  int nsub = nch[seq] * 4;
  int g0 = (b * NCB + chf[seq]) * 4;
  int d = tid >> 4;
  float A_dn = -__expf(p.Alog0[tid]);
  float h = 0.f;
  for (int c = 0; c < nsub; ++c) {
    size_t g = (size_t)(g0 + c);
    float hl = p.hloc[g * 256 + tid];
    float sdv = p.sumdelta[g * 16 + d];
    p.hloc[g * 256 + tid] = h;          // h_start for this sub-chunk
    h = fmaf(__expf(A_dn * sdv), h, hl);
  }
}

// pass 3: rerun scan from h_start, produce y, fuse gate+out-proj+skip+LN+proj, scatter
__global__ __launch_bounds__(256) void k_pass3(Params p) {
  __shared__ float s[SMEM_TOT];
  int bid = blockIdx.x, tid = threadIdx.x;
  int b, seq, l0, Sa;
  decode_bid(bid, b, seq, l0, Sa);
  load_w0(p, s, tid);
  __syncthreads();
  stage1<true>(p, s, b, seq, l0, Sa, tid);
  int w = tid >> 6, lane = tid & 63;
  int d = lane >> 2, ng = lane & 3;
  int t0 = w * SUB;
  int len = Sa - t0; len = len < 0 ? 0 : (len > SUB ? SUB : len);
  int gs = bid * 4 + w;
  float A_[4], h_[4];
  #pragma unroll
  for (int j = 0; j < 4; ++j) {
    A_[j] = s[SW_A + d * 16 + ng * 4 + j];
    h_[j] = p.hloc[(size_t)gs * 256 + d * 16 + ng * 4 + j];   // h_start
  }
  for (int i = 0; i < len; ++i) {
    int t = t0 + i;
    float dl = s[O_DLT + t * 17 + d];    // read delta (before y overwrite below)
    float xv = s[O_XC + t * 17 + d];
    float u = dl * xv;
    float y = 0.f;
    #pragma unroll
    for (int j = 0; j < 4; ++j) {
      float bm = s[O_BM + t * 17 + ng * 4 + j];
      float cm = s[O_XI + t * 17 + ng * 4 + j];
      h_[j] = fmaf(__expf(A_[j] * dl), h_[j], u * bm);
      y = fmaf(h_[j], cm, y);
    }
    y += __shfl_xor(y, 1);
    y += __shfl_xor(y, 2);
    if (ng == 0) s[O_DLT + t * 17 + d] = y;  // reuse delta slot as y (in-order per wave)
  }
  __syncthreads();
  if (tid < Sa) {
    int l = l0 + tid;
    float c8[8];
    gather8(p, b, seq, l, c8);
    float y[16];
    #pragma unroll
    for (int i = 0; i < 16; ++i) {
      float z = 0.f;
      #pragma unroll
      for (int j = 0; j < 8; ++j) z = fmaf(s[SW_IN + (16 + i) * 8 + j], c8[j], z);
      y[i] = (s[O_DLT + tid * 17 + i] + s[O_XC + tid * 17 + i] * s[SW_D + i]) * siluf(z);
    }
    float o[8];
    float sk = s[SW_SKIP];
    #pragma unroll
    for (int m = 0; m < 8; ++m) {
      float a = 0.f;
      #pragma unroll
      for (int dd = 0; dd < 16; ++dd) a = fmaf(s[SW_OUTW + m * 16 + dd], y[dd], a);
      o[m] = a + sk * c8[m];
    }
    float mu = 0.f;
    #pragma unroll
    for (int m = 0; m < 8; ++m) mu += o[m];
    mu *= 0.125f;
    float var = 0.f;
    #pragma unroll
    for (int m = 0; m < 8; ++m) { float t = o[m] - mu; var += t * t; }
    var *= 0.125f;
    float inv = rsqrtf(var + 1e-5f);
    float ln[8];
    #pragma unroll
    for (int m = 0; m < 8; ++m) ln[m] = (o[m] - mu) * inv * s[SW_NG + m] + s[SW_NB + m];
    Loc lc = locate(seq, l);
    int obase = outbase(lc.k) + (b * lc.C + lc.ch) * lc.hw + lc.pos;
    #pragma unroll
    for (int m = 0; m < 8; ++m) {
      float a = s[SW_PB + m];
      #pragma unroll
      for (int j = 0; j < 8; ++j) a = fmaf(s[SW_PW + m * 8 + j], ln[j], a);
      p.out[obase + m * lc.hw] = a;
    }
  }
}

extern "C" void kernel_launch(void* const* d_in, const int* in_sizes, int n_in,
                              void* d_out, int out_size, void* d_ws, size_t ws_size,
                              hipStream_t stream) {
  (void)in_sizes; (void)n_in; (void)out_size; (void)ws_size;
  Params p;
  p.t0 = (const float*)d_in[0];  p.t1 = (const float*)d_in[1];
  p.t2 = (const float*)d_in[2];  p.t3 = (const float*)d_in[3];
  p.t4 = (const float*)d_in[4];
  p.in_w0   = (const float*)d_in[5];
  p.conv_w0 = (const float*)d_in[6];
  p.conv_b0 = (const float*)d_in[7];
  p.xproj0  = (const float*)d_in[8];
  p.dtw0    = (const float*)d_in[9];
  p.dtb0    = (const float*)d_in[10];
  p.Alog0   = (const float*)d_in[11];
  p.D0      = (const float*)d_in[12];
  p.outw0   = (const float*)d_in[13];
  p.in_w1   = (const float*)d_in[14];
  p.conv_w1 = (const float*)d_in[15];
  p.conv_b1 = (const float*)d_in[16];
  p.xproj1  = (const float*)d_in[17];
  p.dtw1    = (const float*)d_in[18];
  p.dtb1    = (const float*)d_in[19];
  p.Alog1   = (const float*)d_in[20];
  p.D1      = (const float*)d_in[21];
  p.outw1   = (const float*)d_in[22];
  p.ng  = (const float*)d_in[23];
  p.nb  = (const float*)d_in[24];
  p.pw  = (const float*)d_in[25];
  p.pb  = (const float*)d_in[26];
  p.n1g = (const float*)d_in[27];
  p.n1b = (const float*)d_in[28];
  p.p1w = (const float*)d_in[29];
  p.p1b = (const float*)d_in[30];
  p.skip = (const float*)d_in[31];
  p.out = (float*)d_out;
  float* ws = (float*)d_ws;
  p.hloc     = ws;                               // NSUB*256 floats (reused as hstart)
  p.sumdelta = ws + (size_t)NSUB * 256;          // NSUB*16 floats  (~6.0 MB total)
  k_pass1<<<dim3(NCHUNK + 8), dim3(256), 0, stream>>>(p);
  k_pass2<<<dim3(32), dim3(256), 0, stream>>>(p);
  k_pass3<<<dim3(NCHUNK), dim3(256), 0, stream>>>(p);
}

// Round 4
// 396.459 us; speedup vs baseline: 1.2629x; 1.1411x over previous
//
#include <hip/hip_runtime.h>
#include <cmath>

// ---- chunking: SCH=168 tokens/chunk, 4 sub-chunks of 42 (one per wave) ----
// m0 sequences L={21824,5440,1344,320} -> chunks {130,33,8,2} per batch
#define SCH 168
#define SUB 42
#define NCB 173      // chunks per batch: 130+33+8+2
#define NCHUNK 1384  // 8 batches
#define NSUB 5536    // 4*NCHUNK
// smem word offsets, m0 path
#define SW_IN 0        // 32x8
#define SW_CONVW 256   // 16x4
#define SW_CONVB 320
#define SW_XPROJ 336   // 33x16
#define SW_DTW 864
#define SW_DTB 880
#define SW_A 896       // 16x16  (A = -exp(Alog))
#define SW_D 1152
#define SW_OUTW 1168   // 8x16
#define SW_NG 1296
#define SW_NB 1304
#define SW_PW 1312     // 8x8
#define SW_PB 1376
#define SW_SKIP 1384
#define O_XI 1385      // 171 rows x 17 (xi; later reused for y in pass3)
#define REC 4292       // 168 token records: [dl16|xc16|bm16|(cm16)] stride 52/68
#define SMEM1 13028    // REC + 168*52 = 52,112 B
#define SMEM3 15716    // REC + 168*68 = 62,864 B (<64KB)
// c5 (m1) path offsets (inside SMEM1)
#define V_IN 0
#define V_CONVW 1024
#define V_CONVB 1152
#define V_XPROJ 1184
#define V_DTW 2240
#define V_DTB 2272
#define V_A 2304
#define V_D 2816
#define V_OUTW 2848
#define V_NG 3360
#define V_NB 3376
#define V_PW 3392
#define V_PB 3648
#define V_SKIP 3664
#define V_XI 3668      // 64x33
#define V_XC 5780      // 64x33
#define V_DL 7892      // 64x33 (delta; y written back post-scan)
#define V_BM 10004     // 64x20 (b128-aligned)
#define V_CM 11284     // 64x20

struct Params {
  const float *t0, *t1, *t2, *t3, *t4;
  const float *in_w0,*conv_w0,*conv_b0,*xproj0,*dtw0,*dtb0,*Alog0,*D0,*outw0;
  const float *in_w1,*conv_w1,*conv_b1,*xproj1,*dtw1,*dtb1,*Alog1,*D1,*outw1;
  const float *ng,*nb,*pw,*pb,*n1g,*n1b,*p1w,*p1b,*skip;
  float* out;
  float *hloc, *sumdelta;   // hloc reused as hstart (pass2 writes in place)
};

__device__ __forceinline__ float softplusf(float x) { return x > 20.f ? x : log1pf(__expf(x)); }
__device__ __forceinline__ float siluf(float x) { return x * (1.f / (1.f + __expf(-x))); }
__device__ __forceinline__ void st4(float* p4, float a, float b, float c, float d) {
  float4 v; v.x = a; v.y = b; v.z = c; v.w = d; *(float4*)p4 = v;
}

struct Loc { int k, pos, ch, hw, C; };

__device__ __forceinline__ Loc locate(int seq, int l) {
  Loc r;
  if (seq == 0) { r.ch = 0;
    if (l < 16384)      { r.k=0; r.pos=l;        r.hw=16384; r.C=8;  }
    else if (l < 20480) { r.k=1; r.pos=l-16384;  r.hw=4096;  r.C=16; }
    else if (l < 21504) { r.k=2; r.pos=l-20480;  r.hw=1024;  r.C=24; }
    else if (l < 21760) { r.k=3; r.pos=l-21504;  r.hw=256;   r.C=32; }
    else                { r.k=4; r.pos=l-21760;  r.hw=64;    r.C=48; }
  } else if (seq == 1) { r.ch = 8;
    if (l < 4096)       { r.k=1; r.pos=l;        r.hw=4096;  r.C=16; }
    else if (l < 5120)  { r.k=2; r.pos=l-4096;   r.hw=1024;  r.C=24; }
    else if (l < 5376)  { r.k=3; r.pos=l-5120;   r.hw=256;   r.C=32; }
    else                { r.k=4; r.pos=l-5376;   r.hw=64;    r.C=48; }
  } else if (seq == 2) { r.ch = 16;
    if (l < 1024)       { r.k=2; r.pos=l;        r.hw=1024;  r.C=24; }
    else if (l < 1280)  { r.k=3; r.pos=l-1024;   r.hw=256;   r.C=32; }
    else                { r.k=4; r.pos=l-1280;   r.hw=64;    r.C=48; }
  } else { r.ch = 24;
    if (l < 256)        { r.k=3; r.pos=l;        r.hw=256;   r.C=32; }
    else                { r.k=4; r.pos=l-256;    r.hw=64;    r.C=48; }
  }
  return r;
}

__device__ __forceinline__ const float* tsel(const Params& p, int k) {
  switch (k) { case 0: return p.t0; case 1: return p.t1; case 2: return p.t2;
               case 3: return p.t3; default: return p.t4; }
}
// flat offsets of output tensors (with batch dim): total 1859584
__device__ __forceinline__ int outbase(int k) {
  switch (k) { case 0: return 0; case 1: return 1048576; case 2: return 1572864;
               case 3: return 1769472; default: return 1835008; }
}

__device__ __forceinline__ void gather8(const Params& p, int b, int seq, int l, float* c) {
  Loc lc = locate(seq, l);
  const float* t = tsel(p, lc.k);
  int base = (b * lc.C + lc.ch) * lc.hw + lc.pos;
  #pragma unroll
  for (int j = 0; j < 8; ++j) c[j] = t[base + j * lc.hw];
}

__device__ __forceinline__ void decode_bid(int bid, int& b, int& seq, int& l0, int& Sa) {
  b = bid / NCB;
  int r = bid - b * NCB;
  int c, L;
  if (r < 130)      { seq = 0; c = r;       L = 21824; }
  else if (r < 163) { seq = 1; c = r - 130; L = 5440;  }
  else if (r < 171) { seq = 2; c = r - 163; L = 1344;  }
  else              { seq = 3; c = r - 171; L = 320;   }
  l0 = c * SCH;
  int rem = L - l0;
  Sa = rem < SCH ? rem : SCH;
}

__device__ void load_w0(const Params& p, float* s, int tid) {
  for (int i = tid; i < 256; i += 256) s[SW_IN + i] = p.in_w0[i];
  for (int i = tid; i < 64;  i += 256) s[SW_CONVW + i] = p.conv_w0[i];
  for (int i = tid; i < 16;  i += 256) s[SW_CONVB + i] = p.conv_b0[i];
  for (int i = tid; i < 528; i += 256) s[SW_XPROJ + i] = p.xproj0[i];
  for (int i = tid; i < 16;  i += 256) s[SW_DTW + i] = p.dtw0[i];
  for (int i = tid; i < 16;  i += 256) s[SW_DTB + i] = p.dtb0[i];
  for (int i = tid; i < 256; i += 256) s[SW_A + i] = -__expf(p.Alog0[i]);
  for (int i = tid; i < 16;  i += 256) s[SW_D + i] = p.D0[i];
  for (int i = tid; i < 128; i += 256) s[SW_OUTW + i] = p.outw0[i];
  for (int i = tid; i < 8;   i += 256) s[SW_NG + i] = p.ng[i];
  for (int i = tid; i < 8;   i += 256) s[SW_NB + i] = p.nb[i];
  for (int i = tid; i < 64;  i += 256) s[SW_PW + i] = p.pw[i];
  for (int i = tid; i < 8;   i += 256) s[SW_PB + i] = p.pb[i];
  if (tid == 0) s[SW_SKIP] = p.skip[0];
}

// chunk front end: gather -> in-proj -> conv -> silu -> x-proj -> softplus.
// Emits per-token RECORD [dl16|xc16|bm16|(cm16)] via conflict-free b128 writes.
// Rows >= Sa are zero-filled => scan steps there are identity (exp(0)=1, add 0).
template <int RSTR, bool WANT_CM>
__device__ void stage1(const Params& p, float* s, int b, int seq, int l0, int Sa, int tid) {
  if (tid < Sa + 3) {                 // rows r <-> token l0-3+r (conv halo)
    int l = l0 - 3 + tid;
    float x8[8];
    if (l >= 0) gather8(p, b, seq, l, x8);
    else {
      #pragma unroll
      for (int j = 0; j < 8; ++j) x8[j] = 0.f;
    }
    #pragma unroll
    for (int i = 0; i < 16; ++i) {
      float a = 0.f;
      #pragma unroll
      for (int j = 0; j < 8; ++j) a = fmaf(s[SW_IN + i * 8 + j], x8[j], a);
      s[O_XI + tid * 17 + i] = a;
    }
  }
  __syncthreads();
  if (tid < Sa) {
    float xc[16];
    #pragma unroll
    for (int i = 0; i < 16; ++i) {
      float a = s[SW_CONVB + i];
      #pragma unroll
      for (int kk = 0; kk < 4; ++kk)
        a = fmaf(s[SW_CONVW + i * 4 + kk], s[O_XI + (tid + kk) * 17 + i], a);
      xc[i] = siluf(a);
    }
    float dt = 0.f;
    #pragma unroll
    for (int i = 0; i < 16; ++i) dt = fmaf(s[SW_XPROJ + i], xc[i], dt);
    float bmv[16], cmv[16], dlv[16];
    #pragma unroll
    for (int n = 0; n < 16; ++n) {
      float a = 0.f;
      #pragma unroll
      for (int i = 0; i < 16; ++i) a = fmaf(s[SW_XPROJ + (1 + n) * 16 + i], xc[i], a);
      bmv[n] = a;
    }
    if (WANT_CM) {
      #pragma unroll
      for (int n = 0; n < 16; ++n) {
        float a = 0.f;
        #pragma unroll
        for (int i = 0; i < 16; ++i) a = fmaf(s[SW_XPROJ + (17 + n) * 16 + i], xc[i], a);
        cmv[n] = a;
      }
    }
    #pragma unroll
    for (int d = 0; d < 16; ++d)
      dlv[d] = softplusf(fmaf(dt, s[SW_DTW + d], s[SW_DTB + d]));
    float* rec = &s[REC + tid * RSTR];
    #pragma unroll
    for (int q = 0; q < 4; ++q) st4(rec + q * 4,      dlv[q*4], dlv[q*4+1], dlv[q*4+2], dlv[q*4+3]);
    #pragma unroll
    for (int q = 0; q < 4; ++q) st4(rec + 16 + q * 4, xc[q*4],  xc[q*4+1],  xc[q*4+2],  xc[q*4+3]);
    #pragma unroll
    for (int q = 0; q < 4; ++q) st4(rec + 32 + q * 4, bmv[q*4], bmv[q*4+1], bmv[q*4+2], bmv[q*4+3]);
    if (WANT_CM) {
      #pragma unroll
      for (int q = 0; q < 4; ++q) st4(rec + 48 + q * 4, cmv[q*4], cmv[q*4+1], cmv[q*4+2], cmv[q*4+3]);
    }
  } else if (tid < SCH) {             // identity records for padding rows
    float* rec = &s[REC + tid * RSTR];
    #pragma unroll
    for (int q = 0; q < (WANT_CM ? 16 : 12); ++q) st4(rec + q * 4, 0.f, 0.f, 0.f, 0.f);
  }
  __syncthreads();
}

// ---- c5 / m1 path: whole sequence (L=64, di=32) in one block ----
__device__ void load_w1(const Params& p, float* s, int tid) {
  for (int i = tid; i < 1024; i += 256) s[V_IN + i] = p.in_w1[i];
  for (int i = tid; i < 128;  i += 256) s[V_CONVW + i] = p.conv_w1[i];
  for (int i = tid; i < 32;   i += 256) s[V_CONVB + i] = p.conv_b1[i];
  for (int i = tid; i < 1056; i += 256) s[V_XPROJ + i] = p.xproj1[i];
  for (int i = tid; i < 32;   i += 256) s[V_DTW + i] = p.dtw1[i];
  for (int i = tid; i < 32;   i += 256) s[V_DTB + i] = p.dtb1[i];
  for (int i = tid; i < 512;  i += 256) s[V_A + i] = -__expf(p.Alog1[i]);
  for (int i = tid; i < 32;   i += 256) s[V_D + i] = p.D1[i];
  for (int i = tid; i < 512;  i += 256) s[V_OUTW + i] = p.outw1[i];
  for (int i = tid; i < 16;   i += 256) s[V_NG + i] = p.n1g[i];
  for (int i = tid; i < 16;   i += 256) s[V_NB + i] = p.n1b[i];
  for (int i = tid; i < 256;  i += 256) s[V_PW + i] = p.p1w[i];
  for (int i = tid; i < 16;   i += 256) s[V_PB + i] = p.p1b[i];
  if (tid == 0) s[V_SKIP] = p.skip[0];
}

__device__ void c5_path(const Params& p, float* s, int b, int tid) {
  load_w1(p, s, tid);
  __syncthreads();
  float x16[16];
  bool act = tid < 64;
  if (act) {
    #pragma unroll
    for (int j = 0; j < 16; ++j) x16[j] = p.t4[(b * 48 + 32 + j) * 64 + tid];
    #pragma unroll
    for (int i = 0; i < 32; ++i) {
      float a = 0.f;
      #pragma unroll
      for (int j = 0; j < 16; ++j) a = fmaf(s[V_IN + i * 16 + j], x16[j], a);
      s[V_XI + tid * 33 + i] = a;
    }
  }
  __syncthreads();
  if (act) {
    float xc[32];
    #pragma unroll
    for (int i = 0; i < 32; ++i) {
      float a = s[V_CONVB + i];
      #pragma unroll
      for (int kk = 0; kk < 4; ++kk) {
        int r = tid + kk - 3;
        if (r >= 0) a = fmaf(s[V_CONVW + i * 4 + kk], s[V_XI + r * 33 + i], a);
      }
      xc[i] = siluf(a);
      s[V_XC + tid * 33 + i] = xc[i];
    }
    float dt = 0.f;
    #pragma unroll
    for (int i = 0; i < 32; ++i) dt = fmaf(s[V_XPROJ + i], xc[i], dt);
    float bmv[16], cmv[16];
    #pragma unroll
    for (int n = 0; n < 16; ++n) {
      float a = 0.f, c = 0.f;
      #pragma unroll
      for (int i = 0; i < 32; ++i) {
        a = fmaf(s[V_XPROJ + (1 + n) * 32 + i], xc[i], a);
        c = fmaf(s[V_XPROJ + (17 + n) * 32 + i], xc[i], c);
      }
      bmv[n] = a; cmv[n] = c;
    }
    float* rb = &s[V_BM + tid * 20];
    float* rc = &s[V_CM + tid * 20];
    #pragma unroll
    for (int q = 0; q < 4; ++q) {
      st4(rb + q * 4, bmv[q*4], bmv[q*4+1], bmv[q*4+2], bmv[q*4+3]);
      st4(rc + q * 4, cmv[q*4], cmv[q*4+1], cmv[q*4+2], cmv[q*4+3]);
    }
    #pragma unroll
    for (int d = 0; d < 32; ++d)
      s[V_DL + tid * 33 + d] = softplusf(fmaf(dt, s[V_DTW + d], s[V_DTB + d]));
  }
  __syncthreads();
  // register-tiled scan: 128 threads = (d 0..31, ng 0..3); tiles of 4 steps.
  if (tid < 128) {
    int d = tid >> 2, ng = tid & 3;
    float4 Av = *(float4*)&s[V_A + d * 16 + ng * 4];
    float h0 = 0.f, h1 = 0.f, h2 = 0.f, h3 = 0.f;
    float yreg[16];
    for (int tile = 0; tile < 16; ++tile) {
      int tb = tile * 4;
      float dl[4], xv[4]; float4 bm[4], cm[4];
      #pragma unroll
      for (int i = 0; i < 4; ++i) {
        dl[i] = s[V_DL + (tb + i) * 33 + d];
        xv[i] = s[V_XC + (tb + i) * 33 + d];
        bm[i] = *(float4*)&s[V_BM + (tb + i) * 20 + ng * 4];
        cm[i] = *(float4*)&s[V_CM + (tb + i) * 20 + ng * 4];
      }
      #pragma unroll
      for (int i = 0; i < 4; ++i) {
        float u = dl[i] * xv[i];
        float e0 = __expf(Av.x * dl[i]), e1 = __expf(Av.y * dl[i]);
        float e2 = __expf(Av.z * dl[i]), e3 = __expf(Av.w * dl[i]);
        h0 = fmaf(e0, h0, u * bm[i].x);
        h1 = fmaf(e1, h1, u * bm[i].y);
        h2 = fmaf(e2, h2, u * bm[i].z);
        h3 = fmaf(e3, h3, u * bm[i].w);
        float y = h0 * cm[i].x;
        y = fmaf(h1, cm[i].y, y); y = fmaf(h2, cm[i].z, y); y = fmaf(h3, cm[i].w, y);
        y += __shfl_xor(y, 1);
        y += __shfl_xor(y, 2);
        if (i == ng) yreg[tile] = y;   // each quad lane holds full sum
      }
    }
    #pragma unroll
    for (int q = 0; q < 16; ++q) s[V_DL + (q * 4 + ng) * 33 + d] = yreg[q];
  }
  __syncthreads();
  if (act) {
    float y[32];
    #pragma unroll
    for (int d = 0; d < 32; ++d) {
      float z = 0.f;
      #pragma unroll
      for (int j = 0; j < 16; ++j) z = fmaf(s[V_IN + (32 + d) * 16 + j], x16[j], z);
      y[d] = (s[V_DL + tid * 33 + d] + s[V_XC + tid * 33 + d] * s[V_D + d]) * siluf(z);
    }
    float o[16];
    float sk = s[V_SKIP];
    #pragma unroll
    for (int m = 0; m < 16; ++m) {
      float a = 0.f;
      #pragma unroll
      for (int d = 0; d < 32; ++d) a = fmaf(s[V_OUTW + m * 32 + d], y[d], a);
      o[m] = a + sk * x16[m];
    }
    float mu = 0.f;
    #pragma unroll
    for (int m = 0; m < 16; ++m) mu += o[m];
    mu *= (1.f / 16.f);
    float var = 0.f;
    #pragma unroll
    for (int m = 0; m < 16; ++m) { float t = o[m] - mu; var += t * t; }
    var *= (1.f / 16.f);
    float inv = rsqrtf(var + 1e-5f);
    float ln[16];
    #pragma unroll
    for (int m = 0; m < 16; ++m) ln[m] = (o[m] - mu) * inv * s[V_NG + m] + s[V_NB + m];
    #pragma unroll
    for (int m = 0; m < 16; ++m) {
      float a = s[V_PB + m];
      #pragma unroll
      for (int j = 0; j < 16; ++j) a = fmaf(s[V_PW + m * 16 + j], ln[j], a);
      p.out[1835008 + (b * 48 + 32 + m) * 64 + tid] = a;
    }
  }
}

// pass 1: per-sub-chunk local scan (h from 0) -> h_local_end + per-d delta sums
__global__ __launch_bounds__(256) void k_pass1(Params p) {
  __shared__ float s[SMEM1];
  int bid = blockIdx.x, tid = threadIdx.x;
  if (bid < 8) { c5_path(p, s, bid, tid); return; }
  int cid = bid - 8;
  int b, seq, l0, Sa;
  decode_bid(cid, b, seq, l0, Sa);
  load_w0(p, s, tid);
  __syncthreads();
  stage1<52, false>(p, s, b, seq, l0, Sa, tid);
  int w = tid >> 6, lane = tid & 63;
  int d = lane >> 2, ng = lane & 3;
  float4 Av = *(float4*)&s[SW_A + d * 16 + ng * 4];
  float h0 = 0.f, h1 = 0.f, h2 = 0.f, h3 = 0.f, sd = 0.f;
  int t0 = w * SUB;
  for (int tile = 0; tile < 7; ++tile) {
    int tb = t0 + tile * 6;
    float dl[6], xv[6]; float4 bm[6];
    #pragma unroll
    for (int i = 0; i < 6; ++i) {
      const float* r = &s[REC + (tb + i) * 52];
      dl[i] = r[d]; xv[i] = r[16 + d];
      bm[i] = *(const float4*)&r[32 + ng * 4];
    }
    #pragma unroll
    for (int i = 0; i < 6; ++i) {
      float u = dl[i] * xv[i];
      float e0 = __expf(Av.x * dl[i]), e1 = __expf(Av.y * dl[i]);
      float e2 = __expf(Av.z * dl[i]), e3 = __expf(Av.w * dl[i]);
      h0 = fmaf(e0, h0, u * bm[i].x);
      h1 = fmaf(e1, h1, u * bm[i].y);
      h2 = fmaf(e2, h2, u * bm[i].z);
      h3 = fmaf(e3, h3, u * bm[i].w);
      sd += dl[i];
    }
  }
  int gs = cid * 4 + w;
  float4 hv; hv.x = h0; hv.y = h1; hv.z = h2; hv.w = h3;
  ((float4*)p.hloc)[(size_t)gs * 64 + lane] = hv;
  if (ng == 0) p.sumdelta[(size_t)gs * 16 + d] = sd;
}

// pass 2: cross-sub-chunk combine, 16-wide load batching (one vmcnt wait / 16 steps)
__global__ __launch_bounds__(256) void k_pass2(Params p) {
  int bid = blockIdx.x, tid = threadIdx.x;
  int b = bid >> 2, seq = bid & 3;
  const int nch[4] = {130, 33, 8, 2};
  const int chf[4] = {0, 130, 163, 171};
  int nsub = nch[seq] * 4;
  int g0 = (b * NCB + chf[seq]) * 4;
  int d = tid >> 4;
  float A_dn = -__expf(p.Alog0[tid]);
  float h = 0.f;
  for (int c0 = 0; c0 < nsub; c0 += 16) {
    float hl[16], sdv[16];
    #pragma unroll
    for (int j = 0; j < 16; ++j) {
      int c = c0 + j; size_t g = (size_t)(g0 + c);
      bool v = c < nsub;
      hl[j]  = v ? p.hloc[g * 256 + tid] : 0.f;
      sdv[j] = v ? p.sumdelta[g * 16 + d] : 0.f;
    }
    #pragma unroll
    for (int j = 0; j < 16; ++j) {
      int c = c0 + j; size_t g = (size_t)(g0 + c);
      if (c < nsub) p.hloc[g * 256 + tid] = h;   // h_start, in place
      h = fmaf(__expf(A_dn * sdv[j]), h, hl[j]);
    }
  }
}

// pass 3: rerun scan from h_start, produce y, fuse gate+out-proj+skip+LN+proj, scatter
__global__ __launch_bounds__(256) void k_pass3(Params p) {
  __shared__ float s[SMEM3];
  int bid = blockIdx.x, tid = threadIdx.x;
  int b, seq, l0, Sa;
  decode_bid(bid, b, seq, l0, Sa);
  load_w0(p, s, tid);
  __syncthreads();
  stage1<68, true>(p, s, b, seq, l0, Sa, tid);
  int w = tid >> 6, lane = tid & 63;
  int d = lane >> 2, ng = lane & 3;
  int t0 = w * SUB;
  int gs = bid * 4 + w;
  float4 Av = *(float4*)&s[SW_A + d * 16 + ng * 4];
  float4 hv = ((float4*)p.hloc)[(size_t)gs * 64 + lane];   // h_start
  float h0 = hv.x, h1 = hv.y, h2 = hv.z, h3 = hv.w;
  float yreg[11];
  for (int tile = 0; tile < 7; ++tile) {
    int tb = t0 + tile * 6;
    float dl[6], xv[6]; float4 bm[6], cm[6];
    #pragma unroll
    for (int i = 0; i < 6; ++i) {
      const float* r = &s[REC + (tb + i) * 68];
      dl[i] = r[d]; xv[i] = r[16 + d];
      bm[i] = *(const float4*)&r[32 + ng * 4];
      cm[i] = *(const float4*)&r[48 + ng * 4];
    }
    #pragma unroll
    for (int i = 0; i < 6; ++i) {
      float u = dl[i] * xv[i];
      float e0 = __expf(Av.x * dl[i]), e1 = __expf(Av.y * dl[i]);
      float e2 = __expf(Av.z * dl[i]), e3 = __expf(Av.w * dl[i]);
      h0 = fmaf(e0, h0, u * bm[i].x);
      h1 = fmaf(e1, h1, u * bm[i].y);
      h2 = fmaf(e2, h2, u * bm[i].z);
      h3 = fmaf(e3, h3, u * bm[i].w);
      float y = h0 * cm[i].x;
      y = fmaf(h1, cm[i].y, y); y = fmaf(h2, cm[i].z, y); y = fmaf(h3, cm[i].w, y);
      y += __shfl_xor(y, 1);
      y += __shfl_xor(y, 2);
      int tr = tile * 6 + i;
      if ((tr & 3) == ng) yreg[tr >> 2] = y;   // retain; quad all hold full sum
    }
  }
  // y -> dead xi region (stride 17); own-wave rows only, after all record reads
  #pragma unroll
  for (int q = 0; q < 11; ++q) {
    int tr = q * 4 + ng;
    if (tr < SUB) s[O_XI + (t0 + tr) * 17 + d] = yreg[q];
  }
  __syncthreads();
  if (tid < Sa) {
    int l = l0 + tid;
    float c8[8];
    gather8(p, b, seq, l, c8);
    const float* rec = &s[REC + tid * 68];
    float y[16];
    #pragma unroll
    for (int i = 0; i < 16; ++i) {
      float z = 0.f;
      #pragma unroll
      for (int j = 0; j < 8; ++j) z = fmaf(s[SW_IN + (16 + i) * 8 + j], c8[j], z);
      y[i] = (s[O_XI + tid * 17 + i] + rec[16 + i] * s[SW_D + i]) * siluf(z);
    }
    float o[8];
    float sk = s[SW_SKIP];
    #pragma unroll
    for (int m = 0; m < 8; ++m) {
      float a = 0.f;
      #pragma unroll
      for (int dd = 0; dd < 16; ++dd) a = fmaf(s[SW_OUTW + m * 16 + dd], y[dd], a);
      o[m] = a + sk * c8[m];
    }
    float mu = 0.f;
    #pragma unroll
    for (int m = 0; m < 8; ++m) mu += o[m];
    mu *= 0.125f;
    float var = 0.f;
    #pragma unroll
    for (int m = 0; m < 8; ++m) { float t = o[m] - mu; var += t * t; }
    var *= 0.125f;
    float inv = rsqrtf(var + 1e-5f);
    float ln[8];
    #pragma unroll
    for (int m = 0; m < 8; ++m) ln[m] = (o[m] - mu) * inv * s[SW_NG + m] + s[SW_NB + m];
    Loc lc = locate(seq, l);
    int obase = outbase(lc.k) + (b * lc.C + lc.ch) * lc.hw + lc.pos;
    #pragma unroll
    for (int m = 0; m < 8; ++m) {
      float a = s[SW_PB + m];
      #pragma unroll
      for (int j = 0; j < 8; ++j) a = fmaf(s[SW_PW + m * 8 + j], ln[j], a);
      p.out[obase + m * lc.hw] = a;
    }
  }
}

extern "C" void kernel_launch(void* const* d_in, const int* in_sizes, int n_in,
                              void* d_out, int out_size, void* d_ws, size_t ws_size,
                              hipStream_t stream) {
  (void)in_sizes; (void)n_in; (void)out_size; (void)ws_size;
  Params p;
  p.t0 = (const float*)d_in[0];  p.t1 = (const float*)d_in[1];
  p.t2 = (const float*)d_in[2];  p.t3 = (const float*)d_in[3];
  p.t4 = (const float*)d_in[4];
  p.in_w0   = (const float*)d_in[5];
  p.conv_w0 = (const float*)d_in[6];
  p.conv_b0 = (const float*)d_in[7];
  p.xproj0  = (const float*)d_in[8];
  p.dtw0    = (const float*)d_in[9];
  p.dtb0    = (const float*)d_in[10];
  p.Alog0   = (const float*)d_in[11];
  p.D0      = (const float*)d_in[12];
  p.outw0   = (const float*)d_in[13];
  p.in_w1   = (const float*)d_in[14];
  p.conv_w1 = (const float*)d_in[15];
  p.conv_b1 = (const float*)d_in[16];
  p.xproj1  = (const float*)d_in[17];
  p.dtw1    = (const float*)d_in[18];
  p.dtb1    = (const float*)d_in[19];
  p.Alog1   = (const float*)d_in[20];
  p.D1      = (const float*)d_in[21];
  p.outw1   = (const float*)d_in[22];
  p.ng  = (const float*)d_in[23];
  p.nb  = (const float*)d_in[24];
  p.pw  = (const float*)d_in[25];
  p.pb  = (const float*)d_in[26];
  p.n1g = (const float*)d_in[27];
  p.n1b = (const float*)d_in[28];
  p.p1w = (const float*)d_in[29];
  p.p1b = (const float*)d_in[30];
  p.skip = (const float*)d_in[31];
  p.out = (float*)d_out;
  float* ws = (float*)d_ws;
  p.hloc     = ws;                               // NSUB*256 floats (reused as hstart)
  p.sumdelta = ws + (size_t)NSUB * 256;          // NSUB*16 floats
  k_pass1<<<dim3(NCHUNK + 8), dim3(256), 0, stream>>>(p);
  k_pass2<<<dim3(32), dim3(256), 0, stream>>>(p);
  k_pass3<<<dim3(NCHUNK), dim3(256), 0, stream>>>(p);
}